// Round 16
// baseline (223.993 us; speedup 1.0000x reference)
//
#include <hip/hip_runtime.h>
#include <hip/hip_fp16.h>
#include <cstdint>

#define DM    1472
#define NH    6
#define DKV   64
#define INNER 384
#define BATCH 4
#define SEQ   2048
#define LOG2E 1.4426950408889634f

typedef __attribute__((ext_vector_type(8))) _Float16 half8;
typedef __attribute__((ext_vector_type(4))) _Float16 half4;
typedef __attribute__((ext_vector_type(4))) float f32x4;

__device__ __forceinline__ void gload16(const void* g, const void* l) {
  __builtin_amdgcn_global_load_lds((const __attribute__((address_space(1))) void*)g,
                                   (__attribute__((address_space(3))) void*)l, 16, 0, 0);
}

// ---------------- prep: weights fp32 -> fp16 transposed ----------------
__global__ void prep_weights(const float* __restrict__ WQ, const float* __restrict__ WK,
                             const float* __restrict__ WV, const float* __restrict__ WO,
                             _Float16* __restrict__ WqT, _Float16* __restrict__ WkT,
                             _Float16* __restrict__ WvT, _Float16* __restrict__ WoT) {
  int idx = blockIdx.x * blockDim.x + threadIdx.x;
  const int per = DM * INNER;
  if (idx >= 4 * per) return;
  int which = idx / per;
  int i = idx - which * per;
  if (which < 3) {
    const float* W = which == 0 ? WQ : (which == 1 ? WK : WV);
    _Float16* T = which == 0 ? WqT : (which == 1 ? WkT : WvT);
    int k = i / INNER, n = i - (i / INNER) * INNER;
    T[(size_t)n * DM + k] = (_Float16)W[i];   // [INNER][DM] = W^T
  } else {
    int k = i / DM, n = i - (i / DM) * DM;
    WoT[(size_t)n * INNER + k] = (_Float16)WO[i];  // [DM][INNER] = WO^T
  }
}

// ---------------- prep: shift-replicated bias table biasS[h][c][4104] ----------------
__global__ void prep_bias(const float* __restrict__ rel_bias, float* __restrict__ biasS) {
  int idx = blockIdx.x * blockDim.x + threadIdx.x;
  const int TOT = NH * 4 * 4104;
  if (idx >= TOT) return;
  int h = idx / (4 * 4104);
  int rem = idx - h * 4 * 4104;
  int cc = rem / 4104;
  int i = rem - cc * 4104;
  int j = i + cc; if (j > 4094) j = 4094;
  int d = j - 2047;                 // relative position k - q
  int ret = d > 0 ? 16 : 0;
  int a = d < 0 ? -d : d;
  int bucket;
  if (a < 8) bucket = ret + a;
  else {
    int large;
    if      (a >= 91) large = 15;
    else if (a >= 64) large = 14;
    else if (a >= 46) large = 13;
    else if (a >= 32) large = 12;
    else if (a >= 23) large = 11;
    else if (a >= 16) large = 10;
    else if (a >= 12) large = 9;
    else              large = 8;
    bucket = ret + large;
  }
  biasS[idx] = rel_bias[bucket * NH + h] * LOG2E;
}

// ---------------- prep: per-64x64-tile mask nonzero flags (exact) ----------------
__global__ __launch_bounds__(256) void prep_maskflags(const float* __restrict__ mask,
                                                      int* __restrict__ flags) {
  const int bid = blockIdx.x;
  const int kh = bid & 1;
  const int qt = (bid >> 1) & 31;
  const int b = bid >> 6;
  const int tid = threadIdx.x;
  __shared__ int fl[16];
  if (tid < 16) fl[tid] = 0;
  __syncthreads();
  const float* base = mask + ((size_t)(b * SEQ + qt * 64)) * SEQ + kh * 1024 + tid * 4;
  bool nz = false;
  for (int q = 0; q < 64; ++q) {
    f32x4 v = *(const f32x4*)(base + (size_t)q * SEQ);
    nz |= (v[0] != 0.f) | (v[1] != 0.f) | (v[2] != 0.f) | (v[3] != 0.f);
  }
  if (nz) fl[tid >> 4] = 1;
  __syncthreads();
  if (tid < 16) flags[(size_t)b * 1024 + qt * 32 + kh * 16 + tid] = fl[tid];
}

// ---------------- projection GEMM v5: 128x192 tile, 512 threads, 384 blocks ----------------
// W stored contiguous [1152][DM]; by 0..5 selects 192-col slice; mat = by>>1 (Q/K/V)
__global__ __launch_bounds__(512, 4) void proj_gemm(
    const float* __restrict__ Xq, const float* __restrict__ Xkv,
    const _Float16* __restrict__ Wall,
    _Float16* __restrict__ Qo, _Float16* __restrict__ Ko, _Float16* __restrict__ Vto) {
  const int bm = blockIdx.x, by = blockIdx.y;   // bm 0..63, by 0..5
  const int mat = by >> 1;
  const float* __restrict__ X = (mat == 0) ? Xq : Xkv;
  const _Float16* __restrict__ WT = Wall + (size_t)by * 192 * DM;

  __shared__ alignas(16) float    As[2][128 * 32];   // 16 KB/buf
  __shared__ alignas(16) _Float16 Bs[2][192 * 32];   // 12 KB/buf => 56 KB total

  const int tid = threadIdx.x;
  const int lane = tid & 63, wave = tid >> 6;        // 8 waves
  const int wm = wave >> 1, wn = wave & 1;           // 4 x 2
  const int l15 = lane & 15, lg = lane >> 4;

  f32x4 acc[2][6] = {};

  // A staging: 16 calls (128 rows, 128B k-rows), 2 calls/wave
  const int aoff = 4 * ((lane & 7) ^ (lane >> 3));
  const float* asrc[2];
#pragma unroll
  for (int c = 0; c < 2; ++c)
    asrc[c] = X + (size_t)(bm * 128 + (wave * 2 + c) * 8 + (lane >> 3)) * DM + aoff;
  // B staging: 12 calls (192 rows, 64B k-rows); waves 0-3 do 2, waves 4-7 do 1
  const int boff = 8 * ((lane & 3) ^ ((lane >> 3) & 3));
  const int nB = (wave < 4) ? 2 : 1;
  const int bcall0 = (wave < 4) ? wave * 2 : 8 + (wave - 4);
  const _Float16* bsrc[2];
  for (int c = 0; c < 2; ++c)
    bsrc[c] = WT + (size_t)((bcall0 + c) * 16 + (lane >> 2)) * DM + boff;

  const int NT = DM / 32;   // 46

  // prologue: batches 0 (buf0) and 1 (buf1)
#pragma unroll
  for (int c = 0; c < 2; ++c)
    gload16(asrc[c], (const char*)&As[0][0] + (wave * 2 + c) * 1024);
  for (int c = 0; c < nB; ++c)
    gload16(bsrc[c], (const char*)&Bs[0][0] + (bcall0 + c) * 1024);
#pragma unroll
  for (int c = 0; c < 2; ++c)
    gload16(asrc[c] + 32, (const char*)&As[1][0] + (wave * 2 + c) * 1024);
  for (int c = 0; c < nB; ++c)
    gload16(bsrc[c] + 32, (const char*)&Bs[1][0] + (bcall0 + c) * 1024);

  for (int t = 0; t < NT; ++t) {
    if (t + 1 < NT) {
      if (wave < 4) asm volatile("s_waitcnt vmcnt(4)" ::: "memory");
      else          asm volatile("s_waitcnt vmcnt(3)" ::: "memory");
    } else {
      asm volatile("s_waitcnt vmcnt(0)" ::: "memory");
    }
    __builtin_amdgcn_s_barrier();
    __builtin_amdgcn_sched_barrier(0);

    const char* Ab = (const char*)&As[t & 1][0];
    const char* Bb = (const char*)&Bs[t & 1][0];
    half8 af[2];
#pragma unroll
    for (int m = 0; m < 2; ++m) {
      int r = wm * 32 + m * 16 + l15;
      int s = (r & 7) << 4;
      f32x4 x0 = *(const f32x4*)(Ab + r * 128 + ((lg * 32) ^ s));
      f32x4 x1 = *(const f32x4*)(Ab + r * 128 + ((lg * 32 + 16) ^ s));
      half8 h;
#pragma unroll
      for (int j = 0; j < 4; ++j) { h[j] = (_Float16)x0[j]; h[4 + j] = (_Float16)x1[j]; }
      af[m] = h;
    }
    half8 bf[6];
#pragma unroll
    for (int n = 0; n < 6; ++n) {
      int r = wn * 96 + n * 16 + l15;
      bf[n] = *(const half8*)(Bb + r * 64 + ((lg * 16) ^ (((r >> 1) & 3) << 4)));
    }

    __builtin_amdgcn_s_setprio(1);
#pragma unroll
    for (int m = 0; m < 2; ++m)
#pragma unroll
      for (int n = 0; n < 6; ++n)
        acc[m][n] = __builtin_amdgcn_mfma_f32_16x16x32_f16(af[m], bf[n], acc[m][n], 0, 0, 0);
    __builtin_amdgcn_s_setprio(0);

    __builtin_amdgcn_sched_barrier(0);
    __builtin_amdgcn_s_barrier();       // all waves done reading buf t&1
    if (t + 2 < NT) {                   // distance-2 prefetch into the freed buffer
      const int kf = (t + 2) * 32;
#pragma unroll
      for (int c = 0; c < 2; ++c)
        gload16(asrc[c] + kf, (const char*)&As[t & 1][0] + (wave * 2 + c) * 1024);
      for (int c = 0; c < nB; ++c)
        gload16(bsrc[c] + kf, (const char*)&Bs[t & 1][0] + (bcall0 + c) * 1024);
    }
  }

  // epilogue
#pragma unroll
  for (int m = 0; m < 2; ++m)
#pragma unroll
    for (int n = 0; n < 6; ++n)
#pragma unroll
      for (int r = 0; r < 4; ++r) {
        int gm = bm * 128 + wm * 32 + m * 16 + lg * 4 + r;
        int col = (by & 1) * 192 + wn * 96 + n * 16 + l15;   // 0..383 within matrix
        int b = gm >> 11, s = gm & 2047;
        int h = col >> 6, dd = col & 63;
        float av = acc[m][n][r];
        if (mat == 0)      Qo[((size_t)(b * NH + h) * SEQ + s) * DKV + dd] = (_Float16)(av * LOG2E);
        else if (mat == 1) Ko[((size_t)(b * NH + h) * SEQ + s) * DKV + dd] = (_Float16)av;
        else               Vto[((size_t)(b * NH + h) * DKV + dd) * SEQ + s] = (_Float16)av;
      }
}

// ---------------- flash attention v10 (unchanged, validated) ----------------
__global__ __launch_bounds__(256, 4) void attn_kernel(
    const _Float16* __restrict__ Q, const _Float16* __restrict__ K, const _Float16* __restrict__ Vt,
    const float* __restrict__ biasS, const float* __restrict__ mask,
    const int* __restrict__ mflags, _Float16* __restrict__ AO) {
  const int bid = blockIdx.x;
  const int g = (bid & 7) * 96 + (bid >> 3);   // XCD swizzle: 3 bh per XCD
  const int bh = g >> 5, qb = g & 31;
  const int b = bh / NH, h = bh - b * NH;
  const int q0 = qb * 64;
  const int NT = SEQ / 64;   // 32

  const int tid = threadIdx.x, lane = tid & 63, wave = tid >> 6;
  const int l15 = lane & 15, lg = lane >> 4;

  __shared__ alignas(16) _Float16 Ks[2][64 * 64];
  __shared__ alignas(16) _Float16 Vs[2][64 * 64];
  __shared__ alignas(16) _Float16 Ps[4][16 * 64];

  const size_t bhS = (size_t)bh * SEQ;
  const int qq = q0 + wave * 16 + l15;

  const _Float16* Qbase = Q + (bhS + q0 + wave * 16) * DKV;
  half8 qf0 = *(const half8*)(Qbase + (size_t)l15 * DKV + lg * 8);
  half8 qf1 = *(const half8*)(Qbase + (size_t)l15 * DKV + 32 + lg * 8);

  const float* maskrow = mask + (size_t)b * SEQ * SEQ + (size_t)qq * SEQ + lg * 4;
  const int c = (3 - l15) & 3;
  const float* bbase = biasS + (size_t)(h * 4 + c) * 4104 + (lg * 4 - qq + 2047 - c);
  const int* mfl = mflags + b * 1024 + qb * 32;

  float m_r = -1e30f, l_acc = 0.f;
  f32x4 oacc[4] = {};

  const int rl = lane >> 3;
  const int sw = ((lane & 7) ^ rl) * 8;
  const _Float16* Kd0 = K + (bhS + wave * 16 + rl) * DKV + sw;
  const _Float16* Kd1 = Kd0 + 8 * DKV;
  const _Float16* Vd0 = Vt + ((size_t)bh * DKV + wave * 16 + rl) * SEQ + sw;
  const _Float16* Vd1 = Vd0 + 8 * SEQ;
  char* KsB = (char*)&Ks[0][0];
  char* VsB = (char*)&Vs[0][0];
  char* PsB = (char*)&Ps[wave][0];
  const int dmaLds = wave * 2048;

  gload16(Kd0, KsB + dmaLds);
  gload16(Kd1, KsB + dmaLds + 1024);
  gload16(Vd0, VsB + dmaLds);
  gload16(Vd1, VsB + dmaLds + 1024);
  gload16(Kd0 + 64 * DKV, KsB + 8192 + dmaLds);
  gload16(Kd1 + 64 * DKV, KsB + 8192 + dmaLds + 1024);
  gload16(Vd0 + 64, VsB + 8192 + dmaLds);
  gload16(Vd1 + 64, VsB + 8192 + dmaLds + 1024);

  for (int t = 0; t < NT; ++t) {
    if (t + 1 < NT) asm volatile("s_waitcnt vmcnt(4)" ::: "memory");
    else            asm volatile("s_waitcnt vmcnt(0)" ::: "memory");
    __builtin_amdgcn_s_barrier();
    __builtin_amdgcn_sched_barrier(0);

    const int mflag = mfl[t];
    const char* Kb = KsB + (t & 1) * 8192;
    const char* Vb = VsB + (t & 1) * 8192;

    f32x4 sacc[4] = {};
    __builtin_amdgcn_s_setprio(1);
#pragma unroll
    for (int nf = 0; nf < 4; ++nf) {
      int kr = nf * 16 + l15;
      const char* rb = Kb + kr * 128;
      half8 kf0 = *(const half8*)(rb + ((lg ^ (kr & 7)) << 4));
      half8 kf1 = *(const half8*)(rb + (((4 + lg) ^ (kr & 7)) << 4));
      sacc[nf] = __builtin_amdgcn_mfma_f32_16x16x32_f16(kf0, qf0, sacc[nf], 0, 0, 0);
      sacc[nf] = __builtin_amdgcn_mfma_f32_16x16x32_f16(kf1, qf1, sacc[nf], 0, 0, 0);
    }
    __builtin_amdgcn_s_setprio(0);

    float sv[4][4], fm[4];
#pragma unroll
    for (int nf = 0; nf < 4; ++nf) {
      f32x4 bv = *(const f32x4*)(bbase + t * 64 + nf * 16);
#pragma unroll
      for (int r = 0; r < 4; ++r)
        sv[nf][r] = sacc[nf][r] + bv[r];
    }
    if (mflag) {
#pragma unroll
      for (int nf = 0; nf < 4; ++nf) {
        f32x4 mv = *(const f32x4*)(maskrow + t * 64 + nf * 16);
#pragma unroll
        for (int r = 0; r < 4; ++r)
          sv[nf][r] += mv[r] * LOG2E;
      }
    }
#pragma unroll
    for (int nf = 0; nf < 4; ++nf)
      fm[nf] = fmaxf(fmaxf(sv[nf][0], sv[nf][1]), fmaxf(sv[nf][2], sv[nf][3]));
    float mx = fmaxf(fmaxf(fm[0], fm[1]), fmaxf(fm[2], fm[3]));
    mx = fmaxf(mx, __shfl_xor(mx, 16));
    mx = fmaxf(mx, __shfl_xor(mx, 32));

    if (!__all(mx <= m_r + 8.0f)) {   // defer-max (T13)
      float mnew = fmaxf(m_r, mx);
      float sc_ = __builtin_amdgcn_exp2f(m_r - mnew);
      m_r = mnew;
      l_acc *= sc_;
      f32x4 scv;
#pragma unroll
      for (int r = 0; r < 4; ++r) scv[r] = __shfl(sc_, lg * 4 + r);
#pragma unroll
      for (int df = 0; df < 4; ++df) oacc[df] *= scv;
    }

    float rs = 0.f;
#pragma unroll
    for (int nf = 0; nf < 4; ++nf) {
      half4 ph;
#pragma unroll
      for (int r = 0; r < 4; ++r) {
        float p = __builtin_amdgcn_exp2f(sv[nf][r] - m_r);
        rs += p;
        ph[r] = (_Float16)p;
      }
      *(half4*)(PsB + l15 * 128 + ((((nf << 1) + (lg >> 1)) ^ (l15 & 7)) << 4) + ((lg & 1) << 3)) = ph;
    }
    l_acc += rs;

    __builtin_amdgcn_s_setprio(1);
#pragma unroll
    for (int ks = 0; ks < 2; ++ks) {
      half8 pa = *(const half8*)(PsB + l15 * 128 + ((((ks << 2) + lg) ^ (l15 & 7)) << 4));
#pragma unroll
      for (int df = 0; df < 4; ++df) {
        int vr = df * 16 + l15;
        half8 vv = *(const half8*)(Vb + vr * 128 + ((((ks << 2) + lg) ^ (vr & 7)) << 4));
        oacc[df] = __builtin_amdgcn_mfma_f32_16x16x32_f16(pa, vv, oacc[df], 0, 0, 0);
      }
    }
    __builtin_amdgcn_s_setprio(0);

    __builtin_amdgcn_sched_barrier(0);
    __builtin_amdgcn_s_barrier();
    if (t + 2 < NT) {
      char* kb = KsB + (t & 1) * 8192 + dmaLds;
      char* vb_ = VsB + (t & 1) * 8192 + dmaLds;
      gload16(Kd0 + (size_t)(t + 2) * 64 * DKV, kb);
      gload16(Kd1 + (size_t)(t + 2) * 64 * DKV, kb + 1024);
      gload16(Vd0 + (t + 2) * 64, vb_);
      gload16(Vd1 + (t + 2) * 64, vb_ + 1024);
    }
  }

  l_acc += __shfl_xor(l_acc, 16);
  l_acc += __shfl_xor(l_acc, 32);
  f32x4 lv;
#pragma unroll
  for (int r = 0; r < 4; ++r) lv[r] = __shfl(l_acc, lg * 4 + r);
#pragma unroll
  for (int df = 0; df < 4; ++df) {
    int dd = df * 16 + l15;
#pragma unroll
    for (int r = 0; r < 4; ++r) {
      int qrow = q0 + wave * 16 + lg * 4 + r;
      AO[((size_t)(b * SEQ + qrow)) * INNER + h * DKV + dd] = (_Float16)(oacc[df][r] / lv[r]);
    }
  }
}

// ---------------- output GEMM v2: 128x192 tile (N padded to 1536), 512 blocks ----------------
__global__ __launch_bounds__(256, 4) void out_gemm(
    const _Float16* __restrict__ A, const _Float16* __restrict__ BT, float* __restrict__ C) {
  __shared__ alignas(16) _Float16 As[2][128 * 32];   //  8 KB/buf
  __shared__ alignas(16) _Float16 Bs[2][192 * 32];   // 12 KB/buf => 40 KB

  const int tid = threadIdx.x, lane = tid & 63, wave = tid >> 6;
  const int wm = wave >> 1, wn = wave & 1;
  const int bm = blockIdx.x, bn = blockIdx.y;
  const int l15 = lane & 15, lg = lane >> 4;

  f32x4 acc[4][6] = {};

  const int rl4 = (lane >> 2) & 3;
  const int soff = ((lane & 3) ^ rl4) * 8;
  // A: 8 calls (128 rows), 2/wave
  const _Float16* ad[2];
#pragma unroll
  for (int c = 0; c < 2; ++c)
    ad[c] = A + (size_t)(bm * 128 + (wave * 2 + c) * 16 + (lane >> 2)) * INNER + soff;
  // B: 12 calls (192 rows, clamped to DM-1), 3/wave
  const _Float16* bd[3];
#pragma unroll
  for (int c = 0; c < 3; ++c) {
    int rg = bn * 192 + (wave * 3 + c) * 16 + (lane >> 2);
    if (rg > DM - 1) rg = DM - 1;
    bd[c] = BT + (size_t)rg * INNER + soff;
  }
  char* AsB = (char*)&As[0][0];
  char* BsB = (char*)&Bs[0][0];
  const int aLds = wave * 2048;
  const int bLds = wave * 3072;

  const int NT = INNER / 32;  // 12

#pragma unroll
  for (int c = 0; c < 2; ++c) gload16(ad[c], AsB + aLds + c * 1024);
#pragma unroll
  for (int c = 0; c < 3; ++c) gload16(bd[c], BsB + bLds + c * 1024);
  __syncthreads();

  for (int t = 0; t < NT; ++t) {
    if (t + 1 < NT) {
      const int nb = (t + 1) & 1;
      const int kf = (t + 1) * 32;
#pragma unroll
      for (int c = 0; c < 2; ++c) gload16(ad[c] + kf, AsB + nb * 8192 + aLds + c * 1024);
#pragma unroll
      for (int c = 0; c < 3; ++c) gload16(bd[c] + kf, BsB + nb * 12288 + bLds + c * 1024);
    }

    const char* Ab = AsB + (t & 1) * 8192;
    const char* Bb = BsB + (t & 1) * 12288;
    half8 af[4], bf[6];
#pragma unroll
    for (int m = 0; m < 4; ++m) {
      int r = wm * 64 + m * 16 + l15;
      af[m] = *(const half8*)(Ab + r * 64 + ((lg ^ (r & 3)) << 4));
    }
#pragma unroll
    for (int n = 0; n < 6; ++n) {
      int r = wn * 96 + n * 16 + l15;
      bf[n] = *(const half8*)(Bb + r * 64 + ((lg ^ (r & 3)) << 4));
    }
    __builtin_amdgcn_s_setprio(1);
#pragma unroll
    for (int m = 0; m < 4; ++m)
#pragma unroll
      for (int n = 0; n < 6; ++n)
        acc[m][n] = __builtin_amdgcn_mfma_f32_16x16x32_f16(af[m], bf[n], acc[m][n], 0, 0, 0);
    __builtin_amdgcn_s_setprio(0);

    __syncthreads();
  }

#pragma unroll
  for (int m = 0; m < 4; ++m)
#pragma unroll
    for (int n = 0; n < 6; ++n)
#pragma unroll
      for (int r = 0; r < 4; ++r) {
        int gm = bm * 128 + wm * 64 + m * 16 + lg * 4 + r;
        int gn = bn * 192 + wn * 96 + n * 16 + l15;
        if (gn < DM) C[(size_t)gm * DM + gn] = acc[m][n][r];
      }
}

// ---------------- launch ----------------
extern "C" void kernel_launch(void* const* d_in, const int* in_sizes, int n_in,
                              void* d_out, int out_size, void* d_ws, size_t ws_size,
                              hipStream_t stream) {
  const float* kv   = (const float*)d_in[0];
  const float* qs   = (const float*)d_in[1];
  const float* mask = (const float*)d_in[2];
  const float* WQ   = (const float*)d_in[3];
  const float* WK   = (const float*)d_in[4];
  const float* WV   = (const float*)d_in[5];
  const float* WO   = (const float*)d_in[6];
  const float* rb   = (const float*)d_in[7];
  float* out = (float*)d_out;
  char* ws = (char*)d_ws;

  const size_t WT_BYTES  = (size_t)INNER * DM * 2;             // 1,130,496
  const size_t QKV_BYTES = (size_t)BATCH * NH * SEQ * DKV * 2; // 6,291,456
  _Float16* WqT = (_Float16*)(ws);                 // WqT,WkT,WvT contiguous => [1152][DM]
  _Float16* WkT = (_Float16*)(ws + WT_BYTES);
  _Float16* WvT = (_Float16*)(ws + 2 * WT_BYTES);
  _Float16* WoT = (_Float16*)(ws + 3 * WT_BYTES);
  _Float16* Qh  = (_Float16*)(ws + 4 * WT_BYTES);
  _Float16* Kh  = (_Float16*)(ws + 4 * WT_BYTES + QKV_BYTES);
  _Float16* Vth = (_Float16*)(ws + 4 * WT_BYTES + 2 * QKV_BYTES);
  _Float16* AO  = (_Float16*)(ws + 4 * WT_BYTES + 3 * QKV_BYTES);
  float* biasS  = (float*)(ws + 4 * WT_BYTES + 4 * QKV_BYTES);
  int* mflags   = (int*)(ws + 4 * WT_BYTES + 4 * QKV_BYTES + (size_t)NH * 4 * 4104 * 4);

  hipLaunchKernelGGL(prep_weights, dim3((4 * DM * INNER + 255) / 256), dim3(256), 0, stream,
                     WQ, WK, WV, WO, WqT, WkT, WvT, WoT);
  hipLaunchKernelGGL(prep_bias, dim3((NH * 4 * 4104 + 255) / 256), dim3(256), 0, stream, rb, biasS);
  hipLaunchKernelGGL(prep_maskflags, dim3(BATCH * 32 * 2), dim3(256), 0, stream, mask, mflags);
  hipLaunchKernelGGL(proj_gemm, dim3(64, 6), dim3(512), 0, stream,
                     qs, kv, WqT, Qh, Kh, Vth);
  hipLaunchKernelGGL(attn_kernel, dim3(768), dim3(256), 0, stream,
                     Qh, Kh, Vth, biasS, mask, mflags, AO);
  hipLaunchKernelGGL(out_gemm, dim3(64, 8), dim3(256), 0, stream, AO, WoT, out);
}

// Round 17
// 182.769 us; speedup vs baseline: 1.2256x; 1.2256x over previous
//
#include <hip/hip_runtime.h>
#include <hip/hip_fp16.h>
#include <cstdint>

#define DM    1472
#define NH    6
#define DKV   64
#define INNER 384
#define BATCH 4
#define SEQ   2048
#define LOG2E 1.4426950408889634f

typedef __attribute__((ext_vector_type(8))) _Float16 half8;
typedef __attribute__((ext_vector_type(4))) _Float16 half4;
typedef __attribute__((ext_vector_type(4))) float f32x4;

__device__ __forceinline__ void gload16(const void* g, const void* l) {
  __builtin_amdgcn_global_load_lds((const __attribute__((address_space(1))) void*)g,
                                   (__attribute__((address_space(3))) void*)l, 16, 0, 0);
}

// ---------------- prep: weights fp32 -> fp16 transposed ----------------
__global__ void prep_weights(const float* __restrict__ WQ, const float* __restrict__ WK,
                             const float* __restrict__ WV, const float* __restrict__ WO,
                             _Float16* __restrict__ WqT, _Float16* __restrict__ WkT,
                             _Float16* __restrict__ WvT, _Float16* __restrict__ WoT) {
  int idx = blockIdx.x * blockDim.x + threadIdx.x;
  const int per = DM * INNER;
  if (idx >= 4 * per) return;
  int which = idx / per;
  int i = idx - which * per;
  if (which < 3) {
    const float* W = which == 0 ? WQ : (which == 1 ? WK : WV);
    _Float16* T = which == 0 ? WqT : (which == 1 ? WkT : WvT);
    int k = i / INNER, n = i - (i / INNER) * INNER;
    T[(size_t)n * DM + k] = (_Float16)W[i];   // [INNER][DM] = W^T
  } else {
    int k = i / DM, n = i - (i / DM) * DM;
    WoT[(size_t)n * INNER + k] = (_Float16)WO[i];  // [DM][INNER] = WO^T
  }
}

// ---------------- prep: shift-replicated bias table biasS[h][c][4104] ----------------
__global__ void prep_bias(const float* __restrict__ rel_bias, float* __restrict__ biasS) {
  int idx = blockIdx.x * blockDim.x + threadIdx.x;
  const int TOT = NH * 4 * 4104;
  if (idx >= TOT) return;
  int h = idx / (4 * 4104);
  int rem = idx - h * 4 * 4104;
  int cc = rem / 4104;
  int i = rem - cc * 4104;
  int j = i + cc; if (j > 4094) j = 4094;
  int d = j - 2047;                 // relative position k - q
  int ret = d > 0 ? 16 : 0;
  int a = d < 0 ? -d : d;
  int bucket;
  if (a < 8) bucket = ret + a;
  else {
    int large;
    if      (a >= 91) large = 15;
    else if (a >= 64) large = 14;
    else if (a >= 46) large = 13;
    else if (a >= 32) large = 12;
    else if (a >= 23) large = 11;
    else if (a >= 16) large = 10;
    else if (a >= 12) large = 9;
    else              large = 8;
    bucket = ret + large;
  }
  biasS[idx] = rel_bias[bucket * NH + h] * LOG2E;
}

// ---------------- prep: per-64x64-tile mask nonzero flags (exact) ----------------
__global__ __launch_bounds__(256) void prep_maskflags(const float* __restrict__ mask,
                                                      int* __restrict__ flags) {
  const int bid = blockIdx.x;
  const int kh = bid & 1;
  const int qt = (bid >> 1) & 31;
  const int b = bid >> 6;
  const int tid = threadIdx.x;
  __shared__ int fl[16];
  if (tid < 16) fl[tid] = 0;
  __syncthreads();
  const float* base = mask + ((size_t)(b * SEQ + qt * 64)) * SEQ + kh * 1024 + tid * 4;
  bool nz = false;
  for (int q = 0; q < 64; ++q) {
    f32x4 v = *(const f32x4*)(base + (size_t)q * SEQ);
    nz |= (v[0] != 0.f) | (v[1] != 0.f) | (v[2] != 0.f) | (v[3] != 0.f);
  }
  if (nz) fl[tid >> 4] = 1;
  __syncthreads();
  if (tid < 16) flags[(size_t)b * 1024 + qt * 32 + kh * 16 + tid] = fl[tid];
}

// ---------------- projection GEMM v5: 128x192 tile, 512 threads, 384 blocks ----------------
__global__ __launch_bounds__(512, 4) void proj_gemm(
    const float* __restrict__ Xq, const float* __restrict__ Xkv,
    const _Float16* __restrict__ Wall,
    _Float16* __restrict__ Qo, _Float16* __restrict__ Ko, _Float16* __restrict__ Vto) {
  const int bm = blockIdx.x, by = blockIdx.y;   // bm 0..63, by 0..5
  const int mat = by >> 1;
  const float* __restrict__ X = (mat == 0) ? Xq : Xkv;
  const _Float16* __restrict__ WT = Wall + (size_t)by * 192 * DM;

  __shared__ alignas(16) float    As[2][128 * 32];   // 16 KB/buf
  __shared__ alignas(16) _Float16 Bs[2][192 * 32];   // 12 KB/buf => 56 KB total

  const int tid = threadIdx.x;
  const int lane = tid & 63, wave = tid >> 6;        // 8 waves
  const int wm = wave >> 1, wn = wave & 1;           // 4 x 2
  const int l15 = lane & 15, lg = lane >> 4;

  f32x4 acc[2][6] = {};

  const int aoff = 4 * ((lane & 7) ^ (lane >> 3));
  const float* asrc[2];
#pragma unroll
  for (int c = 0; c < 2; ++c)
    asrc[c] = X + (size_t)(bm * 128 + (wave * 2 + c) * 8 + (lane >> 3)) * DM + aoff;
  const int boff = 8 * ((lane & 3) ^ ((lane >> 3) & 3));
  const int nB = (wave < 4) ? 2 : 1;
  const int bcall0 = (wave < 4) ? wave * 2 : 8 + (wave - 4);
  const _Float16* bsrc[2];
  for (int c = 0; c < 2; ++c)
    bsrc[c] = WT + (size_t)((bcall0 + c) * 16 + (lane >> 2)) * DM + boff;

  const int NT = DM / 32;   // 46

#pragma unroll
  for (int c = 0; c < 2; ++c)
    gload16(asrc[c], (const char*)&As[0][0] + (wave * 2 + c) * 1024);
  for (int c = 0; c < nB; ++c)
    gload16(bsrc[c], (const char*)&Bs[0][0] + (bcall0 + c) * 1024);
#pragma unroll
  for (int c = 0; c < 2; ++c)
    gload16(asrc[c] + 32, (const char*)&As[1][0] + (wave * 2 + c) * 1024);
  for (int c = 0; c < nB; ++c)
    gload16(bsrc[c] + 32, (const char*)&Bs[1][0] + (bcall0 + c) * 1024);

  for (int t = 0; t < NT; ++t) {
    if (t + 1 < NT) {
      if (wave < 4) asm volatile("s_waitcnt vmcnt(4)" ::: "memory");
      else          asm volatile("s_waitcnt vmcnt(3)" ::: "memory");
    } else {
      asm volatile("s_waitcnt vmcnt(0)" ::: "memory");
    }
    __builtin_amdgcn_s_barrier();
    __builtin_amdgcn_sched_barrier(0);

    const char* Ab = (const char*)&As[t & 1][0];
    const char* Bb = (const char*)&Bs[t & 1][0];
    half8 af[2];
#pragma unroll
    for (int m = 0; m < 2; ++m) {
      int r = wm * 32 + m * 16 + l15;
      int s = (r & 7) << 4;
      f32x4 x0 = *(const f32x4*)(Ab + r * 128 + ((lg * 32) ^ s));
      f32x4 x1 = *(const f32x4*)(Ab + r * 128 + ((lg * 32 + 16) ^ s));
      half8 h;
#pragma unroll
      for (int j = 0; j < 4; ++j) { h[j] = (_Float16)x0[j]; h[4 + j] = (_Float16)x1[j]; }
      af[m] = h;
    }
    half8 bf[6];
#pragma unroll
    for (int n = 0; n < 6; ++n) {
      int r = wn * 96 + n * 16 + l15;
      bf[n] = *(const half8*)(Bb + r * 64 + ((lg * 16) ^ (((r >> 1) & 3) << 4)));
    }

    __builtin_amdgcn_s_setprio(1);
#pragma unroll
    for (int m = 0; m < 2; ++m)
#pragma unroll
      for (int n = 0; n < 6; ++n)
        acc[m][n] = __builtin_amdgcn_mfma_f32_16x16x32_f16(af[m], bf[n], acc[m][n], 0, 0, 0);
    __builtin_amdgcn_s_setprio(0);

    __builtin_amdgcn_sched_barrier(0);
    __builtin_amdgcn_s_barrier();
    if (t + 2 < NT) {
      const int kf = (t + 2) * 32;
#pragma unroll
      for (int c = 0; c < 2; ++c)
        gload16(asrc[c] + kf, (const char*)&As[t & 1][0] + (wave * 2 + c) * 1024);
      for (int c = 0; c < nB; ++c)
        gload16(bsrc[c] + kf, (const char*)&Bs[t & 1][0] + (bcall0 + c) * 1024);
    }
  }

#pragma unroll
  for (int m = 0; m < 2; ++m)
#pragma unroll
    for (int n = 0; n < 6; ++n)
#pragma unroll
      for (int r = 0; r < 4; ++r) {
        int gm = bm * 128 + wm * 32 + m * 16 + lg * 4 + r;
        int col = (by & 1) * 192 + wn * 96 + n * 16 + l15;
        int b = gm >> 11, s = gm & 2047;
        int h = col >> 6, dd = col & 63;
        float av = acc[m][n][r];
        if (mat == 0)      Qo[((size_t)(b * NH + h) * SEQ + s) * DKV + dd] = (_Float16)(av * LOG2E);
        else if (mat == 1) Ko[((size_t)(b * NH + h) * SEQ + s) * DKV + dd] = (_Float16)av;
        else               Vto[((size_t)(b * NH + h) * DKV + dd) * SEQ + s] = (_Float16)av;
      }
}

// ---------------- flash attention v10 (unchanged, validated) ----------------
__global__ __launch_bounds__(256, 4) void attn_kernel(
    const _Float16* __restrict__ Q, const _Float16* __restrict__ K, const _Float16* __restrict__ Vt,
    const float* __restrict__ biasS, const float* __restrict__ mask,
    const int* __restrict__ mflags, _Float16* __restrict__ AO) {
  const int bid = blockIdx.x;
  const int g = (bid & 7) * 96 + (bid >> 3);   // XCD swizzle: 3 bh per XCD
  const int bh = g >> 5, qb = g & 31;
  const int b = bh / NH, h = bh - b * NH;
  const int q0 = qb * 64;
  const int NT = SEQ / 64;   // 32

  const int tid = threadIdx.x, lane = tid & 63, wave = tid >> 6;
  const int l15 = lane & 15, lg = lane >> 4;

  __shared__ alignas(16) _Float16 Ks[2][64 * 64];
  __shared__ alignas(16) _Float16 Vs[2][64 * 64];
  __shared__ alignas(16) _Float16 Ps[4][16 * 64];

  const size_t bhS = (size_t)bh * SEQ;
  const int qq = q0 + wave * 16 + l15;

  const _Float16* Qbase = Q + (bhS + q0 + wave * 16) * DKV;
  half8 qf0 = *(const half8*)(Qbase + (size_t)l15 * DKV + lg * 8);
  half8 qf1 = *(const half8*)(Qbase + (size_t)l15 * DKV + 32 + lg * 8);

  const float* maskrow = mask + (size_t)b * SEQ * SEQ + (size_t)qq * SEQ + lg * 4;
  const int c = (3 - l15) & 3;
  const float* bbase = biasS + (size_t)(h * 4 + c) * 4104 + (lg * 4 - qq + 2047 - c);
  const int* mfl = mflags + b * 1024 + qb * 32;

  float m_r = -1e30f, l_acc = 0.f;
  f32x4 oacc[4] = {};

  const int rl = lane >> 3;
  const int sw = ((lane & 7) ^ rl) * 8;
  const _Float16* Kd0 = K + (bhS + wave * 16 + rl) * DKV + sw;
  const _Float16* Kd1 = Kd0 + 8 * DKV;
  const _Float16* Vd0 = Vt + ((size_t)bh * DKV + wave * 16 + rl) * SEQ + sw;
  const _Float16* Vd1 = Vd0 + 8 * SEQ;
  char* KsB = (char*)&Ks[0][0];
  char* VsB = (char*)&Vs[0][0];
  char* PsB = (char*)&Ps[wave][0];
  const int dmaLds = wave * 2048;

  gload16(Kd0, KsB + dmaLds);
  gload16(Kd1, KsB + dmaLds + 1024);
  gload16(Vd0, VsB + dmaLds);
  gload16(Vd1, VsB + dmaLds + 1024);
  gload16(Kd0 + 64 * DKV, KsB + 8192 + dmaLds);
  gload16(Kd1 + 64 * DKV, KsB + 8192 + dmaLds + 1024);
  gload16(Vd0 + 64, VsB + 8192 + dmaLds);
  gload16(Vd1 + 64, VsB + 8192 + dmaLds + 1024);

  for (int t = 0; t < NT; ++t) {
    if (t + 1 < NT) asm volatile("s_waitcnt vmcnt(4)" ::: "memory");
    else            asm volatile("s_waitcnt vmcnt(0)" ::: "memory");
    __builtin_amdgcn_s_barrier();
    __builtin_amdgcn_sched_barrier(0);

    const int mflag = mfl[t];
    const char* Kb = KsB + (t & 1) * 8192;
    const char* Vb = VsB + (t & 1) * 8192;

    f32x4 sacc[4] = {};
    __builtin_amdgcn_s_setprio(1);
#pragma unroll
    for (int nf = 0; nf < 4; ++nf) {
      int kr = nf * 16 + l15;
      const char* rb = Kb + kr * 128;
      half8 kf0 = *(const half8*)(rb + ((lg ^ (kr & 7)) << 4));
      half8 kf1 = *(const half8*)(rb + (((4 + lg) ^ (kr & 7)) << 4));
      sacc[nf] = __builtin_amdgcn_mfma_f32_16x16x32_f16(kf0, qf0, sacc[nf], 0, 0, 0);
      sacc[nf] = __builtin_amdgcn_mfma_f32_16x16x32_f16(kf1, qf1, sacc[nf], 0, 0, 0);
    }
    __builtin_amdgcn_s_setprio(0);

    float sv[4][4], fm[4];
#pragma unroll
    for (int nf = 0; nf < 4; ++nf) {
      f32x4 bv = *(const f32x4*)(bbase + t * 64 + nf * 16);
#pragma unroll
      for (int r = 0; r < 4; ++r)
        sv[nf][r] = sacc[nf][r] + bv[r];
    }
    if (mflag) {
#pragma unroll
      for (int nf = 0; nf < 4; ++nf) {
        f32x4 mv = *(const f32x4*)(maskrow + t * 64 + nf * 16);
#pragma unroll
        for (int r = 0; r < 4; ++r)
          sv[nf][r] += mv[r] * LOG2E;
      }
    }
#pragma unroll
    for (int nf = 0; nf < 4; ++nf)
      fm[nf] = fmaxf(fmaxf(sv[nf][0], sv[nf][1]), fmaxf(sv[nf][2], sv[nf][3]));
    float mx = fmaxf(fmaxf(fm[0], fm[1]), fmaxf(fm[2], fm[3]));
    mx = fmaxf(mx, __shfl_xor(mx, 16));
    mx = fmaxf(mx, __shfl_xor(mx, 32));

    if (!__all(mx <= m_r + 8.0f)) {   // defer-max (T13)
      float mnew = fmaxf(m_r, mx);
      float sc_ = __builtin_amdgcn_exp2f(m_r - mnew);
      m_r = mnew;
      l_acc *= sc_;
      f32x4 scv;
#pragma unroll
      for (int r = 0; r < 4; ++r) scv[r] = __shfl(sc_, lg * 4 + r);
#pragma unroll
      for (int df = 0; df < 4; ++df) oacc[df] *= scv;
    }

    float rs = 0.f;
#pragma unroll
    for (int nf = 0; nf < 4; ++nf) {
      half4 ph;
#pragma unroll
      for (int r = 0; r < 4; ++r) {
        float p = __builtin_amdgcn_exp2f(sv[nf][r] - m_r);
        rs += p;
        ph[r] = (_Float16)p;
      }
      *(half4*)(PsB + l15 * 128 + ((((nf << 1) + (lg >> 1)) ^ (l15 & 7)) << 4) + ((lg & 1) << 3)) = ph;
    }
    l_acc += rs;

    __builtin_amdgcn_s_setprio(1);
#pragma unroll
    for (int ks = 0; ks < 2; ++ks) {
      half8 pa = *(const half8*)(PsB + l15 * 128 + ((((ks << 2) + lg) ^ (l15 & 7)) << 4));
#pragma unroll
      for (int df = 0; df < 4; ++df) {
        int vr = df * 16 + l15;
        half8 vv = *(const half8*)(Vb + vr * 128 + ((((ks << 2) + lg) ^ (vr & 7)) << 4));
        oacc[df] = __builtin_amdgcn_mfma_f32_16x16x32_f16(pa, vv, oacc[df], 0, 0, 0);
      }
    }
    __builtin_amdgcn_s_setprio(0);

    __builtin_amdgcn_sched_barrier(0);
    __builtin_amdgcn_s_barrier();
    if (t + 2 < NT) {
      char* kb = KsB + (t & 1) * 8192 + dmaLds;
      char* vb_ = VsB + (t & 1) * 8192 + dmaLds;
      gload16(Kd0 + (size_t)(t + 2) * 64 * DKV, kb);
      gload16(Kd1 + (size_t)(t + 2) * 64 * DKV, kb + 1024);
      gload16(Vd0 + (t + 2) * 64, vb_);
      gload16(Vd1 + (t + 2) * 64, vb_ + 1024);
    }
  }

  l_acc += __shfl_xor(l_acc, 16);
  l_acc += __shfl_xor(l_acc, 32);
  f32x4 lv;
#pragma unroll
  for (int r = 0; r < 4; ++r) lv[r] = __shfl(l_acc, lg * 4 + r);
#pragma unroll
  for (int df = 0; df < 4; ++df) {
    int dd = df * 16 + l15;
#pragma unroll
    for (int r = 0; r < 4; ++r) {
      int qrow = q0 + wave * 16 + lg * 4 + r;
      AO[((size_t)(b * SEQ + qrow)) * INNER + h * DKV + dd] = (_Float16)(oacc[df][r] / lv[r]);
    }
  }
}

// ---------------- output GEMM: r12-validated 128x64, gload_lds + dbuf ----------------
__global__ __launch_bounds__(256) void out_gemm(
    const _Float16* __restrict__ A, const _Float16* __restrict__ BT, float* __restrict__ C) {
  __shared__ alignas(16) _Float16 As[2][128 * 32];
  __shared__ alignas(16) _Float16 Bs[2][64 * 32];

  const int tid = threadIdx.x, lane = tid & 63, wave = tid >> 6;
  const int wm = wave >> 1, wn = wave & 1;
  const int bm = blockIdx.x, bn = blockIdx.y;
  const int l15 = lane & 15, lg = lane >> 4;

  f32x4 acc[4][2] = {};

  const int rl4 = (lane >> 2) & 3;
  const int soff = ((lane & 3) ^ rl4) * 8;
  const _Float16* ad0 = A + (size_t)(bm * 128 + (wave * 2) * 16 + (lane >> 2)) * INNER + soff;
  const _Float16* ad1 = ad0 + (size_t)16 * INNER;
  const _Float16* bd0 = BT + (size_t)(bn * 64 + wave * 16 + (lane >> 2)) * INNER + soff;
  char* AsB = (char*)&As[0][0];
  char* BsB = (char*)&Bs[0][0];
  const int aLds = wave * 2048;
  const int bLds = wave * 1024;

  const int NT = INNER / 32;  // 12

  gload16(ad0, AsB + aLds);
  gload16(ad1, AsB + aLds + 1024);
  gload16(bd0, BsB + bLds);
  __syncthreads();

  for (int t = 0; t < NT; ++t) {
    if (t + 1 < NT) {
      const int nb = (t + 1) & 1;
      const int kf = (t + 1) * 32;
      gload16(ad0 + kf, AsB + nb * 8192 + aLds);
      gload16(ad1 + kf, AsB + nb * 8192 + aLds + 1024);
      gload16(bd0 + kf, BsB + nb * 4096 + bLds);
    }

    const char* Ab = AsB + (t & 1) * 8192;
    const char* Bb = BsB + (t & 1) * 4096;
    half8 af[4], bf[2];
#pragma unroll
    for (int m = 0; m < 4; ++m) {
      int r = wm * 64 + m * 16 + l15;
      af[m] = *(const half8*)(Ab + r * 64 + ((lg ^ (r & 3)) << 4));
    }
#pragma unroll
    for (int n = 0; n < 2; ++n) {
      int r = wn * 32 + n * 16 + l15;
      bf[n] = *(const half8*)(Bb + r * 64 + ((lg ^ (r & 3)) << 4));
    }
    __builtin_amdgcn_s_setprio(1);
#pragma unroll
    for (int m = 0; m < 4; ++m)
#pragma unroll
      for (int n = 0; n < 2; ++n)
        acc[m][n] = __builtin_amdgcn_mfma_f32_16x16x32_f16(af[m], bf[n], acc[m][n], 0, 0, 0);
    __builtin_amdgcn_s_setprio(0);

    __syncthreads();
  }

#pragma unroll
  for (int m = 0; m < 4; ++m)
#pragma unroll
    for (int n = 0; n < 2; ++n)
#pragma unroll
      for (int r = 0; r < 4; ++r) {
        int gm = bm * 128 + wm * 64 + m * 16 + lg * 4 + r;
        int gn = bn * 64 + wn * 32 + n * 16 + l15;
        C[(size_t)gm * DM + gn] = acc[m][n][r];
      }
}

// ---------------- launch ----------------
extern "C" void kernel_launch(void* const* d_in, const int* in_sizes, int n_in,
                              void* d_out, int out_size, void* d_ws, size_t ws_size,
                              hipStream_t stream) {
  const float* kv   = (const float*)d_in[0];
  const float* qs   = (const float*)d_in[1];
  const float* mask = (const float*)d_in[2];
  const float* WQ   = (const float*)d_in[3];
  const float* WK   = (const float*)d_in[4];
  const float* WV   = (const float*)d_in[5];
  const float* WO   = (const float*)d_in[6];
  const float* rb   = (const float*)d_in[7];
  float* out = (float*)d_out;
  char* ws = (char*)d_ws;

  const size_t WT_BYTES  = (size_t)INNER * DM * 2;             // 1,130,496
  const size_t QKV_BYTES = (size_t)BATCH * NH * SEQ * DKV * 2; // 6,291,456
  _Float16* WqT = (_Float16*)(ws);                 // WqT,WkT,WvT contiguous => [1152][DM]
  _Float16* WkT = (_Float16*)(ws + WT_BYTES);
  _Float16* WvT = (_Float16*)(ws + 2 * WT_BYTES);
  _Float16* WoT = (_Float16*)(ws + 3 * WT_BYTES);
  _Float16* Qh  = (_Float16*)(ws + 4 * WT_BYTES);
  _Float16* Kh  = (_Float16*)(ws + 4 * WT_BYTES + QKV_BYTES);
  _Float16* Vth = (_Float16*)(ws + 4 * WT_BYTES + 2 * QKV_BYTES);
  _Float16* AO  = (_Float16*)(ws + 4 * WT_BYTES + 3 * QKV_BYTES);
  float* biasS  = (float*)(ws + 4 * WT_BYTES + 4 * QKV_BYTES);
  int* mflags   = (int*)(ws + 4 * WT_BYTES + 4 * QKV_BYTES + (size_t)NH * 4 * 4104 * 4);

  hipLaunchKernelGGL(prep_weights, dim3((4 * DM * INNER + 255) / 256), dim3(256), 0, stream,
                     WQ, WK, WV, WO, WqT, WkT, WvT, WoT);
  hipLaunchKernelGGL(prep_bias, dim3((NH * 4 * 4104 + 255) / 256), dim3(256), 0, stream, rb, biasS);
  hipLaunchKernelGGL(prep_maskflags, dim3(BATCH * 32 * 2), dim3(256), 0, stream, mask, mflags);
  hipLaunchKernelGGL(proj_gemm, dim3(64, 6), dim3(512), 0, stream,
                     qs, kv, WqT, Qh, Kh, Vth);
  hipLaunchKernelGGL(attn_kernel, dim3(768), dim3(256), 0, stream,
                     Qh, Kh, Vth, biasS, mask, mflags, AO);
  hipLaunchKernelGGL(out_gemm, dim3(64, 23), dim3(256), 0, stream, AO, WoT, out);
}

// Round 18
// 171.047 us; speedup vs baseline: 1.3095x; 1.0685x over previous
//
#include <hip/hip_runtime.h>
#include <hip/hip_fp16.h>
#include <cstdint>

#define DM    1472
#define NH    6
#define DKV   64
#define INNER 384
#define BATCH 4
#define SEQ   2048
#define LOG2E 1.4426950408889634f

typedef __attribute__((ext_vector_type(8))) _Float16 half8;
typedef __attribute__((ext_vector_type(4))) _Float16 half4;
typedef __attribute__((ext_vector_type(4))) float f32x4;

__device__ __forceinline__ void gload16(const void* g, const void* l) {
  __builtin_amdgcn_global_load_lds((const __attribute__((address_space(1))) void*)g,
                                   (__attribute__((address_space(3))) void*)l, 16, 0, 0);
}

// ---------------- prep: weights fp32 -> fp16 transposed (LDS-tiled, coalesced) ----------------
// grid (23, 6, 4): z selects WQ/WK/WV/WO. 64x64 tiles.
__global__ __launch_bounds__(256) void prep_weights(const float* __restrict__ WQ, const float* __restrict__ WK,
                             const float* __restrict__ WV, const float* __restrict__ WO,
                             _Float16* __restrict__ WqT, _Float16* __restrict__ WkT,
                             _Float16* __restrict__ WvT, _Float16* __restrict__ WoT) {
  const int z = blockIdx.z;
  const float* __restrict__ W = (z == 0) ? WQ : (z == 1) ? WK : (z == 2) ? WV : WO;
  _Float16* __restrict__ T = (z == 0) ? WqT : (z == 1) ? WkT : (z == 2) ? WvT : WoT;
  const int Krows = (z < 3) ? DM : INNER;     // rows of W == cols of T (row length of T)
  const int Ncols = (z < 3) ? INNER : DM;     // cols of W == rows of T
  const int kt = (z < 3) ? blockIdx.x : blockIdx.y;   // 23 or 6 tiles
  const int nt = (z < 3) ? blockIdx.y : blockIdx.x;   // 6 or 23 tiles
  const int k0 = kt * 64, n0 = nt * 64;

  __shared__ _Float16 ld[64][72];   // padded rows to spread banks
  const int tid = threadIdx.x;

  // coalesced read: thread t covers rows (t>>4)+16p, cols (t&15)*4..+3 (f32x4)
  const int rr = tid >> 4, cc = (tid & 15) * 4;
#pragma unroll
  for (int p = 0; p < 4; ++p) {
    int r = rr + p * 16;
    f32x4 v = *(const f32x4*)(W + (size_t)(k0 + r) * Ncols + n0 + cc);
#pragma unroll
    for (int j = 0; j < 4; ++j) ld[r][cc + j] = (_Float16)v[j];
  }
  __syncthreads();

  // coalesced write: thread t writes T row n0+(t>>2), cols k0+(t&3)*16..+15 (2x half8)
  const int rw = tid >> 2, cw = (tid & 3) * 16;
  half8 o0, o1;
#pragma unroll
  for (int j = 0; j < 8; ++j) { o0[j] = ld[cw + j][rw]; o1[j] = ld[cw + 8 + j][rw]; }
  _Float16* dst = T + (size_t)(n0 + rw) * Krows + k0 + cw;
  *(half8*)dst = o0;
  *(half8*)(dst + 8) = o1;
}

// ---------------- prep: shift-replicated bias table biasS[h][c][4104] ----------------
__global__ void prep_bias(const float* __restrict__ rel_bias, float* __restrict__ biasS) {
  int idx = blockIdx.x * blockDim.x + threadIdx.x;
  const int TOT = NH * 4 * 4104;
  if (idx >= TOT) return;
  int h = idx / (4 * 4104);
  int rem = idx - h * 4 * 4104;
  int cc = rem / 4104;
  int i = rem - cc * 4104;
  int j = i + cc; if (j > 4094) j = 4094;
  int d = j - 2047;                 // relative position k - q
  int ret = d > 0 ? 16 : 0;
  int a = d < 0 ? -d : d;
  int bucket;
  if (a < 8) bucket = ret + a;
  else {
    int large;
    if      (a >= 91) large = 15;
    else if (a >= 64) large = 14;
    else if (a >= 46) large = 13;
    else if (a >= 32) large = 12;
    else if (a >= 23) large = 11;
    else if (a >= 16) large = 10;
    else if (a >= 12) large = 9;
    else              large = 8;
    bucket = ret + large;
  }
  biasS[idx] = rel_bias[bucket * NH + h] * LOG2E;
}

// ---------------- prep: per-64x64-tile mask nonzero flags (exact) ----------------
__global__ __launch_bounds__(256) void prep_maskflags(const float* __restrict__ mask,
                                                      int* __restrict__ flags) {
  const int bid = blockIdx.x;
  const int kh = bid & 1;
  const int qt = (bid >> 1) & 31;
  const int b = bid >> 6;
  const int tid = threadIdx.x;
  __shared__ int fl[16];
  if (tid < 16) fl[tid] = 0;
  __syncthreads();
  const float* base = mask + ((size_t)(b * SEQ + qt * 64)) * SEQ + kh * 1024 + tid * 4;
  bool nz = false;
  for (int q = 0; q < 64; ++q) {
    f32x4 v = *(const f32x4*)(base + (size_t)q * SEQ);
    nz |= (v[0] != 0.f) | (v[1] != 0.f) | (v[2] != 0.f) | (v[3] != 0.f);
  }
  if (nz) fl[tid >> 4] = 1;
  __syncthreads();
  if (tid < 16) flags[(size_t)b * 1024 + qt * 32 + kh * 16 + tid] = fl[tid];
}

// ---------------- projection GEMM v5: 128x192 tile, 512 threads, 384 blocks ----------------
__global__ __launch_bounds__(512, 4) void proj_gemm(
    const float* __restrict__ Xq, const float* __restrict__ Xkv,
    const _Float16* __restrict__ Wall,
    _Float16* __restrict__ Qo, _Float16* __restrict__ Ko, _Float16* __restrict__ Vto) {
  const int bm = blockIdx.x, by = blockIdx.y;   // bm 0..63, by 0..5
  const int mat = by >> 1;
  const float* __restrict__ X = (mat == 0) ? Xq : Xkv;
  const _Float16* __restrict__ WT = Wall + (size_t)by * 192 * DM;

  __shared__ alignas(16) float    As[2][128 * 32];   // 16 KB/buf
  __shared__ alignas(16) _Float16 Bs[2][192 * 32];   // 12 KB/buf => 56 KB total

  const int tid = threadIdx.x;
  const int lane = tid & 63, wave = tid >> 6;        // 8 waves
  const int wm = wave >> 1, wn = wave & 1;           // 4 x 2
  const int l15 = lane & 15, lg = lane >> 4;

  f32x4 acc[2][6] = {};

  const int aoff = 4 * ((lane & 7) ^ (lane >> 3));
  const float* asrc[2];
#pragma unroll
  for (int c = 0; c < 2; ++c)
    asrc[c] = X + (size_t)(bm * 128 + (wave * 2 + c) * 8 + (lane >> 3)) * DM + aoff;
  const int boff = 8 * ((lane & 3) ^ ((lane >> 3) & 3));
  const int nB = (wave < 4) ? 2 : 1;
  const int bcall0 = (wave < 4) ? wave * 2 : 8 + (wave - 4);
  const _Float16* bsrc[2];
  for (int c = 0; c < 2; ++c)
    bsrc[c] = WT + (size_t)((bcall0 + c) * 16 + (lane >> 2)) * DM + boff;

  const int NT = DM / 32;   // 46

#pragma unroll
  for (int c = 0; c < 2; ++c)
    gload16(asrc[c], (const char*)&As[0][0] + (wave * 2 + c) * 1024);
  for (int c = 0; c < nB; ++c)
    gload16(bsrc[c], (const char*)&Bs[0][0] + (bcall0 + c) * 1024);
#pragma unroll
  for (int c = 0; c < 2; ++c)
    gload16(asrc[c] + 32, (const char*)&As[1][0] + (wave * 2 + c) * 1024);
  for (int c = 0; c < nB; ++c)
    gload16(bsrc[c] + 32, (const char*)&Bs[1][0] + (bcall0 + c) * 1024);

  for (int t = 0; t < NT; ++t) {
    if (t + 1 < NT) {
      if (wave < 4) asm volatile("s_waitcnt vmcnt(4)" ::: "memory");
      else          asm volatile("s_waitcnt vmcnt(3)" ::: "memory");
    } else {
      asm volatile("s_waitcnt vmcnt(0)" ::: "memory");
    }
    __builtin_amdgcn_s_barrier();
    __builtin_amdgcn_sched_barrier(0);

    const char* Ab = (const char*)&As[t & 1][0];
    const char* Bb = (const char*)&Bs[t & 1][0];
    half8 af[2];
#pragma unroll
    for (int m = 0; m < 2; ++m) {
      int r = wm * 32 + m * 16 + l15;
      int s = (r & 7) << 4;
      f32x4 x0 = *(const f32x4*)(Ab + r * 128 + ((lg * 32) ^ s));
      f32x4 x1 = *(const f32x4*)(Ab + r * 128 + ((lg * 32 + 16) ^ s));
      half8 h;
#pragma unroll
      for (int j = 0; j < 4; ++j) { h[j] = (_Float16)x0[j]; h[4 + j] = (_Float16)x1[j]; }
      af[m] = h;
    }
    half8 bf[6];
#pragma unroll
    for (int n = 0; n < 6; ++n) {
      int r = wn * 96 + n * 16 + l15;
      bf[n] = *(const half8*)(Bb + r * 64 + ((lg * 16) ^ (((r >> 1) & 3) << 4)));
    }

    __builtin_amdgcn_s_setprio(1);
#pragma unroll
    for (int m = 0; m < 2; ++m)
#pragma unroll
      for (int n = 0; n < 6; ++n)
        acc[m][n] = __builtin_amdgcn_mfma_f32_16x16x32_f16(af[m], bf[n], acc[m][n], 0, 0, 0);
    __builtin_amdgcn_s_setprio(0);

    __builtin_amdgcn_sched_barrier(0);
    __builtin_amdgcn_s_barrier();
    if (t + 2 < NT) {
      const int kf = (t + 2) * 32;
#pragma unroll
      for (int c = 0; c < 2; ++c)
        gload16(asrc[c] + kf, (const char*)&As[t & 1][0] + (wave * 2 + c) * 1024);
      for (int c = 0; c < nB; ++c)
        gload16(bsrc[c] + kf, (const char*)&Bs[t & 1][0] + (bcall0 + c) * 1024);
    }
  }

#pragma unroll
  for (int m = 0; m < 2; ++m)
#pragma unroll
    for (int n = 0; n < 6; ++n)
#pragma unroll
      for (int r = 0; r < 4; ++r) {
        int gm = bm * 128 + wm * 32 + m * 16 + lg * 4 + r;
        int col = (by & 1) * 192 + wn * 96 + n * 16 + l15;
        int b = gm >> 11, s = gm & 2047;
        int h = col >> 6, dd = col & 63;
        float av = acc[m][n][r];
        if (mat == 0)      Qo[((size_t)(b * NH + h) * SEQ + s) * DKV + dd] = (_Float16)(av * LOG2E);
        else if (mat == 1) Ko[((size_t)(b * NH + h) * SEQ + s) * DKV + dd] = (_Float16)av;
        else               Vto[((size_t)(b * NH + h) * DKV + dd) * SEQ + s] = (_Float16)av;
      }
}

// ---------------- flash attention v10 (unchanged, validated) ----------------
__global__ __launch_bounds__(256, 4) void attn_kernel(
    const _Float16* __restrict__ Q, const _Float16* __restrict__ K, const _Float16* __restrict__ Vt,
    const float* __restrict__ biasS, const float* __restrict__ mask,
    const int* __restrict__ mflags, _Float16* __restrict__ AO) {
  const int bid = blockIdx.x;
  const int g = (bid & 7) * 96 + (bid >> 3);   // XCD swizzle: 3 bh per XCD
  const int bh = g >> 5, qb = g & 31;
  const int b = bh / NH, h = bh - b * NH;
  const int q0 = qb * 64;
  const int NT = SEQ / 64;   // 32

  const int tid = threadIdx.x, lane = tid & 63, wave = tid >> 6;
  const int l15 = lane & 15, lg = lane >> 4;

  __shared__ alignas(16) _Float16 Ks[2][64 * 64];
  __shared__ alignas(16) _Float16 Vs[2][64 * 64];
  __shared__ alignas(16) _Float16 Ps[4][16 * 64];

  const size_t bhS = (size_t)bh * SEQ;
  const int qq = q0 + wave * 16 + l15;

  const _Float16* Qbase = Q + (bhS + q0 + wave * 16) * DKV;
  half8 qf0 = *(const half8*)(Qbase + (size_t)l15 * DKV + lg * 8);
  half8 qf1 = *(const half8*)(Qbase + (size_t)l15 * DKV + 32 + lg * 8);

  const float* maskrow = mask + (size_t)b * SEQ * SEQ + (size_t)qq * SEQ + lg * 4;
  const int c = (3 - l15) & 3;
  const float* bbase = biasS + (size_t)(h * 4 + c) * 4104 + (lg * 4 - qq + 2047 - c);
  const int* mfl = mflags + b * 1024 + qb * 32;

  float m_r = -1e30f, l_acc = 0.f;
  f32x4 oacc[4] = {};

  const int rl = lane >> 3;
  const int sw = ((lane & 7) ^ rl) * 8;
  const _Float16* Kd0 = K + (bhS + wave * 16 + rl) * DKV + sw;
  const _Float16* Kd1 = Kd0 + 8 * DKV;
  const _Float16* Vd0 = Vt + ((size_t)bh * DKV + wave * 16 + rl) * SEQ + sw;
  const _Float16* Vd1 = Vd0 + 8 * SEQ;
  char* KsB = (char*)&Ks[0][0];
  char* VsB = (char*)&Vs[0][0];
  char* PsB = (char*)&Ps[wave][0];
  const int dmaLds = wave * 2048;

  gload16(Kd0, KsB + dmaLds);
  gload16(Kd1, KsB + dmaLds + 1024);
  gload16(Vd0, VsB + dmaLds);
  gload16(Vd1, VsB + dmaLds + 1024);
  gload16(Kd0 + 64 * DKV, KsB + 8192 + dmaLds);
  gload16(Kd1 + 64 * DKV, KsB + 8192 + dmaLds + 1024);
  gload16(Vd0 + 64, VsB + 8192 + dmaLds);
  gload16(Vd1 + 64, VsB + 8192 + dmaLds + 1024);

  for (int t = 0; t < NT; ++t) {
    if (t + 1 < NT) asm volatile("s_waitcnt vmcnt(4)" ::: "memory");
    else            asm volatile("s_waitcnt vmcnt(0)" ::: "memory");
    __builtin_amdgcn_s_barrier();
    __builtin_amdgcn_sched_barrier(0);

    const int mflag = mfl[t];
    const char* Kb = KsB + (t & 1) * 8192;
    const char* Vb = VsB + (t & 1) * 8192;

    f32x4 sacc[4] = {};
    __builtin_amdgcn_s_setprio(1);
#pragma unroll
    for (int nf = 0; nf < 4; ++nf) {
      int kr = nf * 16 + l15;
      const char* rb = Kb + kr * 128;
      half8 kf0 = *(const half8*)(rb + ((lg ^ (kr & 7)) << 4));
      half8 kf1 = *(const half8*)(rb + (((4 + lg) ^ (kr & 7)) << 4));
      sacc[nf] = __builtin_amdgcn_mfma_f32_16x16x32_f16(kf0, qf0, sacc[nf], 0, 0, 0);
      sacc[nf] = __builtin_amdgcn_mfma_f32_16x16x32_f16(kf1, qf1, sacc[nf], 0, 0, 0);
    }
    __builtin_amdgcn_s_setprio(0);

    float sv[4][4], fm[4];
#pragma unroll
    for (int nf = 0; nf < 4; ++nf) {
      f32x4 bv = *(const f32x4*)(bbase + t * 64 + nf * 16);
#pragma unroll
      for (int r = 0; r < 4; ++r)
        sv[nf][r] = sacc[nf][r] + bv[r];
    }
    if (mflag) {
#pragma unroll
      for (int nf = 0; nf < 4; ++nf) {
        f32x4 mv = *(const f32x4*)(maskrow + t * 64 + nf * 16);
#pragma unroll
        for (int r = 0; r < 4; ++r)
          sv[nf][r] += mv[r] * LOG2E;
      }
    }
#pragma unroll
    for (int nf = 0; nf < 4; ++nf)
      fm[nf] = fmaxf(fmaxf(sv[nf][0], sv[nf][1]), fmaxf(sv[nf][2], sv[nf][3]));
    float mx = fmaxf(fmaxf(fm[0], fm[1]), fmaxf(fm[2], fm[3]));
    mx = fmaxf(mx, __shfl_xor(mx, 16));
    mx = fmaxf(mx, __shfl_xor(mx, 32));

    if (!__all(mx <= m_r + 8.0f)) {   // defer-max (T13)
      float mnew = fmaxf(m_r, mx);
      float sc_ = __builtin_amdgcn_exp2f(m_r - mnew);
      m_r = mnew;
      l_acc *= sc_;
      f32x4 scv;
#pragma unroll
      for (int r = 0; r < 4; ++r) scv[r] = __shfl(sc_, lg * 4 + r);
#pragma unroll
      for (int df = 0; df < 4; ++df) oacc[df] *= scv;
    }

    float rs = 0.f;
#pragma unroll
    for (int nf = 0; nf < 4; ++nf) {
      half4 ph;
#pragma unroll
      for (int r = 0; r < 4; ++r) {
        float p = __builtin_amdgcn_exp2f(sv[nf][r] - m_r);
        rs += p;
        ph[r] = (_Float16)p;
      }
      *(half4*)(PsB + l15 * 128 + ((((nf << 1) + (lg >> 1)) ^ (l15 & 7)) << 4) + ((lg & 1) << 3)) = ph;
    }
    l_acc += rs;

    __builtin_amdgcn_s_setprio(1);
#pragma unroll
    for (int ks = 0; ks < 2; ++ks) {
      half8 pa = *(const half8*)(PsB + l15 * 128 + ((((ks << 2) + lg) ^ (l15 & 7)) << 4));
#pragma unroll
      for (int df = 0; df < 4; ++df) {
        int vr = df * 16 + l15;
        half8 vv = *(const half8*)(Vb + vr * 128 + ((((ks << 2) + lg) ^ (vr & 7)) << 4));
        oacc[df] = __builtin_amdgcn_mfma_f32_16x16x32_f16(pa, vv, oacc[df], 0, 0, 0);
      }
    }
    __builtin_amdgcn_s_setprio(0);

    __builtin_amdgcn_sched_barrier(0);
    __builtin_amdgcn_s_barrier();
    if (t + 2 < NT) {
      char* kb = KsB + (t & 1) * 8192 + dmaLds;
      char* vb_ = VsB + (t & 1) * 8192 + dmaLds;
      gload16(Kd0 + (size_t)(t + 2) * 64 * DKV, kb);
      gload16(Kd1 + (size_t)(t + 2) * 64 * DKV, kb + 1024);
      gload16(Vd0 + (t + 2) * 64, vb_);
      gload16(Vd1 + (t + 2) * 64, vb_ + 1024);
    }
  }

  l_acc += __shfl_xor(l_acc, 16);
  l_acc += __shfl_xor(l_acc, 32);
  f32x4 lv;
#pragma unroll
  for (int r = 0; r < 4; ++r) lv[r] = __shfl(l_acc, lg * 4 + r);
#pragma unroll
  for (int df = 0; df < 4; ++df) {
    int dd = df * 16 + l15;
#pragma unroll
    for (int r = 0; r < 4; ++r) {
      int qrow = q0 + wave * 16 + lg * 4 + r;
      AO[((size_t)(b * SEQ + qrow)) * INNER + h * DKV + dd] = (_Float16)(oacc[df][r] / lv[r]);
    }
  }
}

// ---------------- output GEMM: r12-validated 128x64, gload_lds + dbuf ----------------
__global__ __launch_bounds__(256) void out_gemm(
    const _Float16* __restrict__ A, const _Float16* __restrict__ BT, float* __restrict__ C) {
  __shared__ alignas(16) _Float16 As[2][128 * 32];
  __shared__ alignas(16) _Float16 Bs[2][64 * 32];

  const int tid = threadIdx.x, lane = tid & 63, wave = tid >> 6;
  const int wm = wave >> 1, wn = wave & 1;
  const int bm = blockIdx.x, bn = blockIdx.y;
  const int l15 = lane & 15, lg = lane >> 4;

  f32x4 acc[4][2] = {};

  const int rl4 = (lane >> 2) & 3;
  const int soff = ((lane & 3) ^ rl4) * 8;
  const _Float16* ad0 = A + (size_t)(bm * 128 + (wave * 2) * 16 + (lane >> 2)) * INNER + soff;
  const _Float16* ad1 = ad0 + (size_t)16 * INNER;
  const _Float16* bd0 = BT + (size_t)(bn * 64 + wave * 16 + (lane >> 2)) * INNER + soff;
  char* AsB = (char*)&As[0][0];
  char* BsB = (char*)&Bs[0][0];
  const int aLds = wave * 2048;
  const int bLds = wave * 1024;

  const int NT = INNER / 32;  // 12

  gload16(ad0, AsB + aLds);
  gload16(ad1, AsB + aLds + 1024);
  gload16(bd0, BsB + bLds);
  __syncthreads();

  for (int t = 0; t < NT; ++t) {
    if (t + 1 < NT) {
      const int nb = (t + 1) & 1;
      const int kf = (t + 1) * 32;
      gload16(ad0 + kf, AsB + nb * 8192 + aLds);
      gload16(ad1 + kf, AsB + nb * 8192 + aLds + 1024);
      gload16(bd0 + kf, BsB + nb * 4096 + bLds);
    }

    const char* Ab = AsB + (t & 1) * 8192;
    const char* Bb = BsB + (t & 1) * 4096;
    half8 af[4], bf[2];
#pragma unroll
    for (int m = 0; m < 4; ++m) {
      int r = wm * 64 + m * 16 + l15;
      af[m] = *(const half8*)(Ab + r * 64 + ((lg ^ (r & 3)) << 4));
    }
#pragma unroll
    for (int n = 0; n < 2; ++n) {
      int r = wn * 32 + n * 16 + l15;
      bf[n] = *(const half8*)(Bb + r * 64 + ((lg ^ (r & 3)) << 4));
    }
    __builtin_amdgcn_s_setprio(1);
#pragma unroll
    for (int m = 0; m < 4; ++m)
#pragma unroll
      for (int n = 0; n < 2; ++n)
        acc[m][n] = __builtin_amdgcn_mfma_f32_16x16x32_f16(af[m], bf[n], acc[m][n], 0, 0, 0);
    __builtin_amdgcn_s_setprio(0);

    __syncthreads();
  }

#pragma unroll
  for (int m = 0; m < 4; ++m)
#pragma unroll
    for (int n = 0; n < 2; ++n)
#pragma unroll
      for (int r = 0; r < 4; ++r) {
        int gm = bm * 128 + wm * 64 + m * 16 + lg * 4 + r;
        int gn = bn * 64 + wn * 32 + n * 16 + l15;
        C[(size_t)gm * DM + gn] = acc[m][n][r];
      }
}

// ---------------- launch ----------------
extern "C" void kernel_launch(void* const* d_in, const int* in_sizes, int n_in,
                              void* d_out, int out_size, void* d_ws, size_t ws_size,
                              hipStream_t stream) {
  const float* kv   = (const float*)d_in[0];
  const float* qs   = (const float*)d_in[1];
  const float* mask = (const float*)d_in[2];
  const float* WQ   = (const float*)d_in[3];
  const float* WK   = (const float*)d_in[4];
  const float* WV   = (const float*)d_in[5];
  const float* WO   = (const float*)d_in[6];
  const float* rb   = (const float*)d_in[7];
  float* out = (float*)d_out;
  char* ws = (char*)d_ws;

  const size_t WT_BYTES  = (size_t)INNER * DM * 2;             // 1,130,496
  const size_t QKV_BYTES = (size_t)BATCH * NH * SEQ * DKV * 2; // 6,291,456
  _Float16* WqT = (_Float16*)(ws);                 // WqT,WkT,WvT contiguous => [1152][DM]
  _Float16* WkT = (_Float16*)(ws + WT_BYTES);
  _Float16* WvT = (_Float16*)(ws + 2 * WT_BYTES);
  _Float16* WoT = (_Float16*)(ws + 3 * WT_BYTES);
  _Float16* Qh  = (_Float16*)(ws + 4 * WT_BYTES);
  _Float16* Kh  = (_Float16*)(ws + 4 * WT_BYTES + QKV_BYTES);
  _Float16* Vth = (_Float16*)(ws + 4 * WT_BYTES + 2 * QKV_BYTES);
  _Float16* AO  = (_Float16*)(ws + 4 * WT_BYTES + 3 * QKV_BYTES);
  float* biasS  = (float*)(ws + 4 * WT_BYTES + 4 * QKV_BYTES);
  int* mflags   = (int*)(ws + 4 * WT_BYTES + 4 * QKV_BYTES + (size_t)NH * 4 * 4104 * 4);

  hipLaunchKernelGGL(prep_weights, dim3(23, 6, 4), dim3(256), 0, stream,
                     WQ, WK, WV, WO, WqT, WkT, WvT, WoT);
  hipLaunchKernelGGL(prep_bias, dim3((NH * 4 * 4104 + 255) / 256), dim3(256), 0, stream, rb, biasS);
  hipLaunchKernelGGL(prep_maskflags, dim3(BATCH * 32 * 2), dim3(256), 0, stream, mask, mflags);
  hipLaunchKernelGGL(proj_gemm, dim3(64, 6), dim3(512), 0, stream,
                     qs, kv, WqT, Qh, Kh, Vth);
  hipLaunchKernelGGL(attn_kernel, dim3(768), dim3(256), 0, stream,
                     Qh, Kh, Vth, biasS, mask, mflags, AO);
  hipLaunchKernelGGL(out_gemm, dim3(64, 23), dim3(256), 0, stream, AO, WoT, out);
}